// Round 9
// baseline (356.855 us; speedup 1.0000x reference)
//
#include <hip/hip_runtime.h>
#include <cstdint>
#include <cstddef>

#define NB 2
#define NN 4096
#define ND 256

typedef __attribute__((ext_vector_type(8))) _Float16 half8;
typedef __attribute__((ext_vector_type(4))) _Float16 half4;
typedef __attribute__((ext_vector_type(4))) float f32x4;

__device__ __forceinline__ f32x4 mfma_16x16x32(half8 a, half8 b, f32x4 c) {
    return __builtin_amdgcn_mfma_f32_16x16x32_f16(a, b, c, 0, 0, 0);
}

// ---------------- conversions ----------------
__global__ __launch_bounds__(256) void k_cvt_h(const float* __restrict__ h,
                                               _Float16* __restrict__ h16) {
    const int i = blockIdx.x * 256 + threadIdx.x;
    f32x4 v = ((const f32x4*)h)[i];
    half4 o;
    o[0] = (_Float16)v[0]; o[1] = (_Float16)v[1];
    o[2] = (_Float16)v[2]; o[3] = (_Float16)v[3];
    ((half4*)h16)[i] = o;
}

__global__ __launch_bounds__(256) void k_wt(const float* __restrict__ W0, const float* __restrict__ W1,
                                            const float* __restrict__ W2, const float* __restrict__ W3,
                                            _Float16* __restrict__ T0, _Float16* __restrict__ T1,
                                            _Float16* __restrict__ T2, _Float16* __restrict__ T3) {
    const int m = blockIdx.y;
    const float* W = m == 0 ? W0 : m == 1 ? W1 : m == 2 ? W2 : W3;
    _Float16* T    = m == 0 ? T0 : m == 1 ? T1 : m == 2 ? T2 : T3;
    const int k = blockIdx.x, j = threadIdx.x;
    T[j * ND + k] = (_Float16)W[k * ND + j];
}

// ---------------- GEMM core (projections / output) ----------------
__device__ __forceinline__ void gemm_core(const _Float16* __restrict__ A,
                                          const _Float16* __restrict__ Bt,
                                          int row0, int l16, int lg, f32x4 acc[16]) {
    #pragma unroll
    for (int i = 0; i < 16; ++i) acc[i] = (f32x4)0.0f;
    #pragma unroll
    for (int ks = 0; ks < 8; ++ks) {
        half8 a = *(const half8*)(A + (size_t)(row0 + l16) * ND + ks * 32 + lg * 8);
        #pragma unroll
        for (int ct = 0; ct < 16; ++ct) {
            half8 b = *(const half8*)(Bt + (size_t)(ct * 16 + l16) * ND + ks * 32 + lg * 8);
            acc[ct] = mfma_16x16x32(a, b, acc[ct]);
        }
    }
}

__global__ __launch_bounds__(256) void k_proj(const _Float16* __restrict__ h16,
                                              const _Float16* __restrict__ Wlt,
                                              const _Float16* __restrict__ Wgt,
                                              const _Float16* __restrict__ Wvt,
                                              _Float16* __restrict__ zn,
                                              _Float16* __restrict__ zg,
                                              _Float16* __restrict__ v16,
                                              float* __restrict__ sq) {
    const int mode = blockIdx.y;
    const _Float16* Bt = mode == 0 ? Wlt : mode == 1 ? Wgt : Wvt;
    _Float16* o16      = mode == 0 ? zn  : mode == 1 ? zg  : v16;
    const int w = threadIdx.x >> 6, l = threadIdx.x & 63;
    const int l16 = l & 15, lg = l >> 4;
    const int row0 = blockIdx.x * 64 + w * 16;
    f32x4 acc[16];
    gemm_core(h16, Bt, row0, l16, lg, acc);

    if (mode == 2) {
        #pragma unroll
        for (int ct = 0; ct < 16; ++ct)
            #pragma unroll
            for (int r = 0; r < 4; ++r)
                o16[(size_t)(row0 + lg * 4 + r) * ND + ct * 16 + l16] = (_Float16)acc[ct][r];
        return;
    }
    float n2[4] = {0.f, 0.f, 0.f, 0.f};
    #pragma unroll
    for (int ct = 0; ct < 16; ++ct)
        #pragma unroll
        for (int r = 0; r < 4; ++r) n2[r] += acc[ct][r] * acc[ct][r];
    #pragma unroll
    for (int m = 1; m < 16; m <<= 1) {
        #pragma unroll
        for (int r = 0; r < 4; ++r) n2[r] += __shfl_xor(n2[r], m);
    }
    if (mode == 0) {
        float ri[4];
        #pragma unroll
        for (int r = 0; r < 4; ++r) ri[r] = 1.0f / fmaxf(sqrtf(n2[r]), 1e-8f);
        #pragma unroll
        for (int ct = 0; ct < 16; ++ct)
            #pragma unroll
            for (int r = 0; r < 4; ++r)
                o16[(size_t)(row0 + lg * 4 + r) * ND + ct * 16 + l16] =
                    (_Float16)(acc[ct][r] * ri[r]);
    } else {
        #pragma unroll
        for (int ct = 0; ct < 16; ++ct)
            #pragma unroll
            for (int r = 0; r < 4; ++r)
                o16[(size_t)(row0 + lg * 4 + r) * ND + ct * 16 + l16] = (_Float16)acc[ct][r];
        if (l16 == 0) {
            #pragma unroll
            for (int r = 0; r < 4; ++r) sq[row0 + lg * 4 + r] = n2[r];
        }
    }
}

// v16 [b][n][d] -> vT [b][d][n]
__global__ __launch_bounds__(256) void k_tr(const _Float16* __restrict__ v16,
                                            _Float16* __restrict__ vT) {
    __shared__ _Float16 t[64][72];
    const int b = blockIdx.z, n0 = blockIdx.x * 64, d0 = blockIdx.y * 64;
    const int tj = threadIdx.x & 63, ti = threadIdx.x >> 6;
    #pragma unroll
    for (int i = 0; i < 16; ++i)
        t[ti + i * 4][tj] = v16[(size_t)(b * NN + n0 + ti + i * 4) * ND + d0 + tj];
    __syncthreads();
    #pragma unroll
    for (int i = 0; i < 16; ++i)
        vT[(size_t)(b * ND + d0 + ti + i * 4) * NN + n0 + tj] = t[tj][ti + i * 4];
}

// ---------------- fused score+PV kernel -------------------------------------
// Block (512 thr, 8 waves) = (b, mat, tq, chunk c of CHUNK tk-tiles).
// Per tk: S^T GEMM with BOTH operand fragments read directly from global
// (row-contiguous 16B) -- no LDS, no barriers in the S phase. Transform writes
// P[q][k] f16 to LDS (stride 272B). PV: O^T[d][q] = V^T * P^T, A-frags from vT
// (global), B-frags from P-LDS; accumulates IN REGISTERS across the chunk.
// S roles: wr=w>>2 (k-half 64), wc=w&3 (q-quarter 32). PV: wave owns d[w*32,+32).
__global__ __launch_bounds__(512, 4) void k_spv(
        const _Float16* __restrict__ zn, const _Float16* __restrict__ zg,
        const _Float16* __restrict__ vT, const float* __restrict__ sqg,
        _Float16* __restrict__ part, float* __restrict__ degpart,
        int CHUNK, int NSLOT) {
    // decode flat slot (tq descending -> longest chunks dispatch first)
    int s = blockIdx.x;
    int tq = 31, c = 0;
    for (;;) {
        const int nc = (tq + CHUNK) / CHUNK;     // ceil((tq+1)/CHUNK)
        if (s < nc) { c = s; break; }
        s -= nc; --tq;
    }
    const int b = blockIdx.y, mat = blockIdx.z;
    const int bm = b * 2 + mat;
    const int tk0 = c * CHUNK;
    const int tkE = (tk0 + CHUNK < tq + 1) ? tk0 + CHUNK : tq + 1;

    const char* z = (const char*)((mat ? zg : zn) + (size_t)b * NN * ND);
    const char* vTb = (const char*)(vT + (size_t)b * ND * NN);
    const float* sqb = sqg + (size_t)b * NN;

    const int w = threadIdx.x >> 6, lane = threadIdx.x & 63;
    const int l16 = lane & 15, lg = lane >> 4;
    const int wr = w >> 2, wc = w & 3;

    __shared__ char P[128 * 272];                // [q][k] f16, 272B row stride

    f32x4 acc_pv[2][8];
    #pragma unroll
    for (int i = 0; i < 2; ++i)
        #pragma unroll
        for (int j = 0; j < 8; ++j) acc_pv[i][j] = (f32x4)0.f;
    float dsum[2] = {0.f, 0.f};

    const char* zq0 = z + (size_t)(tq * 128 + wc * 32 + l16) * 512;
    float sqq[2];
    if (mat) {
        #pragma unroll
        for (int qi = 0; qi < 2; ++qi)
            sqq[qi] = sqb[tq * 128 + wc * 32 + qi * 16 + l16];
    }

    for (int tk = tk0; tk < tkE; ++tk) {
        // ---- S phase: direct-global fragments, no barriers
        f32x4 acc_s[4][2];
        #pragma unroll
        for (int i = 0; i < 4; ++i)
            #pragma unroll
            for (int j = 0; j < 2; ++j) acc_s[i][j] = (f32x4)0.f;
        const char* zk0 = z + (size_t)(tk * 128 + wr * 64 + l16) * 512;
        #pragma unroll
        for (int ks = 0; ks < 8; ++ks) {
            half8 bq[2];
            #pragma unroll
            for (int qi = 0; qi < 2; ++qi)
                bq[qi] = *(const half8*)(zq0 + (size_t)qi * 16 * 512 + ks * 64 + lg * 16);
            #pragma unroll
            for (int di = 0; di < 4; ++di) {
                half8 a = *(const half8*)(zk0 + (size_t)di * 16 * 512 + ks * 64 + lg * 16);
                #pragma unroll
                for (int qi = 0; qi < 2; ++qi)
                    acc_s[di][qi] = mfma_16x16x32(a, bq[qi], acc_s[di][qi]);
            }
        }
        __syncthreads();                         // all waves done reading P (prev PV)
        // ---- transform + P write
        #pragma unroll
        for (int di = 0; di < 4; ++di) {
            const int kl = wr * 64 + di * 16 + lg * 4;
            const int kg = tk * 128 + kl;
            f32x4 sqk;
            if (mat) sqk = *(const f32x4*)(sqb + kg);
            #pragma unroll
            for (int qi = 0; qi < 2; ++qi) {
                const int qloc = wc * 32 + qi * 16 + l16;
                const int qg = tq * 128 + qloc;
                half4 hv;
                #pragma unroll
                for (int r = 0; r < 4; ++r) {
                    const bool msk = (kg + r) < qg;          // causal + zero-diag
                    float p;
                    if (mat) p = msk ? __expf(-0.5f * (sqq[qi] + sqk[r] - 2.f * acc_s[di][qi][r])) : 0.f;
                    else     p = msk ? fmaxf(acc_s[di][qi][r], 0.f) : 0.f;
                    dsum[qi] += p;
                    hv[r] = (_Float16)p;
                }
                *(half4*)(&P[0] + qloc * 272 + kl * 2) = hv;
            }
        }
        __syncthreads();                         // P published
        // ---- PV: wave d-range [w*32,+32), K=128 from P-LDS + vT global
        #pragma unroll
        for (int ks = 0; ks < 4; ++ks) {
            half8 av[2];
            #pragma unroll
            for (int dt = 0; dt < 2; ++dt)
                av[dt] = *(const half8*)(vTb + (size_t)(w * 32 + dt * 16 + l16) * (NN * 2)
                                         + (size_t)(tk * 128 + ks * 32 + lg * 8) * 2);
            #pragma unroll
            for (int qt = 0; qt < 8; ++qt) {
                half8 bp = *(const half8*)(&P[0] + (qt * 16 + l16) * 272 + (ks * 32 + lg * 8) * 2);
                #pragma unroll
                for (int dt = 0; dt < 2; ++dt)
                    acc_pv[dt][qt] = mfma_16x16x32(av[dt], bp, acc_pv[dt][qt]);
            }
        }
    }

    // ---- write O-partial [128 q][256 d] f16
    _Float16* sl = part + ((size_t)bm * NSLOT + blockIdx.x) * 32768;
    #pragma unroll
    for (int dt = 0; dt < 2; ++dt) {
        const int d0 = w * 32 + dt * 16 + lg * 4;
        #pragma unroll
        for (int qt = 0; qt < 8; ++qt) {
            half4 hv;
            #pragma unroll
            for (int r = 0; r < 4; ++r) hv[r] = (_Float16)acc_pv[dt][qt][r];
            *(half4*)(sl + (size_t)(qt * 16 + l16) * 256 + d0) = hv;
        }
    }
    // ---- degree partials (accumulated over chunk in regs)
    #pragma unroll
    for (int qi = 0; qi < 2; ++qi) {
        dsum[qi] += __shfl_xor(dsum[qi], 16);
        dsum[qi] += __shfl_xor(dsum[qi], 32);
    }
    if (lg == 0) {
        #pragma unroll
        for (int qi = 0; qi < 2; ++qi)
            degpart[(size_t)((bm * 32 + tq) * 8 + c) * 256 + wr * 128 + wc * 32 + qi * 16 + l16] = dsum[qi];
    }
}

// ---------------- deg: sum chunk/wave partials (deterministic) ----------------
__global__ __launch_bounds__(128) void k_deg(const float* __restrict__ degpart,
                                             float* __restrict__ deg, int CHUNK) {
    const int bm = blockIdx.x >> 5, tq = blockIdx.x & 31;
    const int nc = (tq + CHUNK) / CHUNK;
    const float* dp = degpart + (size_t)((bm * 32 + tq) * 8) * 256 + threadIdx.x;
    float s = 0.f;
    for (int c = 0; c < nc; ++c)
        s += dp[(size_t)c * 256] + dp[(size_t)c * 256 + 128];
    deg[(size_t)bm * NN + tq * 128 + threadIdx.x] = s;
}

// ---------------- combine partials, normalize, emit ot ----------------
__global__ __launch_bounds__(256) void k_combine2(const _Float16* __restrict__ part,
                                                  const float* __restrict__ deg,
                                                  _Float16* __restrict__ ot,
                                                  int CHUNK, int NSLOT) {
    const int tq = blockIdx.x, b = blockIdx.y;
    int off = 0;                                  // slots for tq' > tq (desc order)
    for (int t = 31; t > tq; --t) off += (t + CHUNK) / CHUNK;
    const int nc = (tq + CHUNK) / CHUNK;
    const _Float16* pl = part + ((size_t)(b * 2 + 0) * NSLOT + off) * 32768;
    const _Float16* pg = part + ((size_t)(b * 2 + 1) * NSLOT + off) * 32768;
    const float* degl = deg + (size_t)(b * 2 + 0) * NN + tq * 128;
    const float* degg = deg + (size_t)(b * 2 + 1) * NN + tq * 128;
    for (int it = 0; it < 16; ++it) {
        const int e = (it * 256 + threadIdx.x) * 8;       // 32768 f16 per tile
        const int row = e >> 8;
        float s_l[8] = {0,0,0,0,0,0,0,0}, s_g[8] = {0,0,0,0,0,0,0,0};
        for (int c = 0; c < nc; ++c) {
            half8 xl = *(const half8*)(pl + (size_t)c * 32768 + e);
            half8 xg = *(const half8*)(pg + (size_t)c * 32768 + e);
            #pragma unroll
            for (int k = 0; k < 8; ++k) { s_l[k] += (float)xl[k]; s_g[k] += (float)xg[k]; }
        }
        const float rl = 0.9f / fmaxf(degl[row], 1e-8f);  // w_l = 1 - T_WAKE
        const float rg = 0.1f / fmaxf(degg[row], 1e-8f);  // w_g = T_WAKE
        half8 o;
        #pragma unroll
        for (int k = 0; k < 8; ++k) o[k] = (_Float16)(rl * s_l[k] + rg * s_g[k]);
        *(half8*)(ot + (size_t)(b * NN + tq * 128 + row) * ND + (e & 255)) = o;
    }
}

// ---------------- final @ Wo ----------------
__global__ __launch_bounds__(256) void k_out(const _Float16* __restrict__ ot,
                                             const _Float16* __restrict__ Wot,
                                             float* __restrict__ out) {
    const int w = threadIdx.x >> 6, l = threadIdx.x & 63;
    const int l16 = l & 15, lg = l >> 4;
    const int row0 = blockIdx.x * 64 + w * 16;
    f32x4 acc[16];
    gemm_core(ot, Wot, row0, l16, lg, acc);
    #pragma unroll
    for (int ct = 0; ct < 16; ++ct)
        #pragma unroll
        for (int r = 0; r < 4; ++r)
            out[(size_t)(row0 + lg * 4 + r) * ND + ct * 16 + l16] = acc[ct][r];
}

extern "C" void kernel_launch(void* const* d_in, const int* in_sizes, int n_in,
                              void* d_out, int out_size, void* d_ws, size_t ws_size,
                              hipStream_t stream) {
    const float* h  = (const float*)d_in[0];
    const float* Wl = (const float*)d_in[2];
    const float* Wg = (const float*)d_in[3];
    const float* Wv = (const float*)d_in[4];
    const float* Wo = (const float*)d_in[5];
    float* out = (float*)d_out;

    uint8_t* base = (uint8_t*)d_ws;
    size_t off = 0;
    auto alloc = [&](size_t bytes) -> void* {
        void* r = base + off;
        off = (off + bytes + 255) & ~(size_t)255;
        return r;
    };
    const size_t bnd = (size_t)NB * NN * ND;
    _Float16* h16 = (_Float16*)alloc(bnd * 2);     // reused as vT after k_proj
    _Float16* Wlt = (_Float16*)alloc(ND * ND * 2);
    _Float16* Wgt = (_Float16*)alloc(ND * ND * 2);
    _Float16* Wvt = (_Float16*)alloc(ND * ND * 2);
    _Float16* Wot = (_Float16*)alloc(ND * ND * 2);
    _Float16* zn  = (_Float16*)alloc(bnd * 2);
    _Float16* zg  = (_Float16*)alloc(bnd * 2);
    _Float16* v16 = (_Float16*)alloc(bnd * 2);
    _Float16* ot  = (_Float16*)alloc(bnd * 2);
    float*    sq  = (float*)alloc((size_t)NB * NN * 4);
    float* degpart = (float*)alloc((size_t)NB * 2 * 32 * 8 * 256 * 4);    // 2 MB
    float* deg     = (float*)alloc((size_t)NB * 2 * NN * 4);              // 64 KB
    _Float16* vT = h16;                            // alias: h16 dead after k_proj

    // chunking with ws fallback (partials: NB*2*NSLOT*64KB)
    int CHUNK = 4, NSLOT = 0;
    for (;;) {
        NSLOT = 0;
        for (int t = 0; t < 32; ++t) NSLOT += (t + CHUNK) / CHUNK;
        if (off + (size_t)NB * 2 * NSLOT * 32768 * 2 + 256 <= ws_size || CHUNK >= 32) break;
        CHUNK *= 2;
    }
    _Float16* part = (_Float16*)alloc((size_t)NB * 2 * NSLOT * 32768 * 2);

    k_cvt_h<<<bnd / 4 / 256, 256, 0, stream>>>(h, h16);
    k_wt<<<dim3(ND, 4), 256, 0, stream>>>(Wl, Wg, Wv, Wo, Wlt, Wgt, Wvt, Wot);
    k_proj<<<dim3(NB * NN / 64, 3), 256, 0, stream>>>(h16, Wlt, Wgt, Wvt, zn, zg, v16, sq);
    k_tr<<<dim3(NN / 64, ND / 64, NB), 256, 0, stream>>>(v16, vT);
    k_spv<<<dim3(NSLOT, NB, 2), 512, 0, stream>>>(zn, zg, vT, sq, part, degpart, CHUNK, NSLOT);
    k_deg<<<NB * 2 * 32, 128, 0, stream>>>(degpart, deg, CHUNK);
    k_combine2<<<dim3(32, NB), 256, 0, stream>>>(part, deg, ot, CHUNK, NSLOT);
    k_out<<<NB * NN / 64, 256, 0, stream>>>(ot, Wot, out);
}

// Round 10
// 192.326 us; speedup vs baseline: 1.8555x; 1.8555x over previous
//
#include <hip/hip_runtime.h>
#include <cstdint>
#include <cstddef>

#define NB 2
#define NN 4096
#define ND 256
#define TRI 528   // 32*33/2 causal 128-tiles per (batch, mat)
#define NPAIR 272 // sum over tq of ceil((tq+1)/2)

typedef __attribute__((ext_vector_type(8))) _Float16 half8;
typedef __attribute__((ext_vector_type(4))) _Float16 half4;
typedef __attribute__((ext_vector_type(4))) float f32x4;

using gas_ptr = const __attribute__((address_space(1))) void*;
using las_ptr = __attribute__((address_space(3))) void*;

__device__ __host__ __forceinline__ int tri32(int t) { return t * (t + 1) / 2; }

__device__ __forceinline__ f32x4 mfma_16x16x32(half8 a, half8 b, f32x4 c) {
    return __builtin_amdgcn_mfma_f32_16x16x32_f16(a, b, c, 0, 0, 0);
}

// counted-vmcnt barriers (6 global_load_lds per STAGE in k_score; 4 in k_pv)
#define BAR_V6() asm volatile("s_waitcnt vmcnt(6) lgkmcnt(0)\n\ts_barrier" ::: "memory")
#define BAR_V4() asm volatile("s_waitcnt vmcnt(4) lgkmcnt(0)\n\ts_barrier" ::: "memory")
#define BAR_V0() asm volatile("s_waitcnt vmcnt(0) lgkmcnt(0)\n\ts_barrier" ::: "memory")

// ---- 128-row x 64B staging side, paired-row swizzle (2 logical rows / 128B) ----
__device__ __forceinline__ void stage_side(const char* __restrict__ gb, size_t rstride,
                                           char* lb) {
    #pragma unroll
    for (int i = 0; i < 2; ++i) {
        const int o = threadIdx.x * 16 + i * 4096;
        const int rp = o >> 7;
        const int uw = (o & 127) ^ ((rp & 7) << 4);
        const int r = rp * 2 + (uw >> 6);
        const int c = uw & 63;
        __builtin_amdgcn_global_load_lds((gas_ptr)(gb + (size_t)r * rstride + c),
                                         (las_ptr)(lb + o), 16, 0, 0);
    }
}

__device__ __forceinline__ half8 ldsfrag(const char* lb, int row, int lg) {
    const int rp = row >> 1;
    const int x = (((row & 1) << 6) + (lg << 4)) ^ ((rp & 7) << 4);
    return *(const half8*)(lb + rp * 128 + x);
}

// ---------------- conversions ----------------
__global__ __launch_bounds__(256) void k_cvt_h(const float* __restrict__ h,
                                               _Float16* __restrict__ h16) {
    const int i = blockIdx.x * 256 + threadIdx.x;
    f32x4 v = ((const f32x4*)h)[i];
    half4 o;
    o[0] = (_Float16)v[0]; o[1] = (_Float16)v[1];
    o[2] = (_Float16)v[2]; o[3] = (_Float16)v[3];
    ((half4*)h16)[i] = o;
}

__global__ __launch_bounds__(256) void k_wt(const float* __restrict__ W0, const float* __restrict__ W1,
                                            const float* __restrict__ W2, const float* __restrict__ W3,
                                            _Float16* __restrict__ T0, _Float16* __restrict__ T1,
                                            _Float16* __restrict__ T2, _Float16* __restrict__ T3) {
    const int m = blockIdx.y;
    const float* W = m == 0 ? W0 : m == 1 ? W1 : m == 2 ? W2 : W3;
    _Float16* T    = m == 0 ? T0 : m == 1 ? T1 : m == 2 ? T2 : T3;
    const int k = blockIdx.x, j = threadIdx.x;
    T[j * ND + k] = (_Float16)W[k * ND + j];
}

// ---------------- GEMM core (projections) ----------------
__device__ __forceinline__ void gemm_core(const _Float16* __restrict__ A,
                                          const _Float16* __restrict__ Bt,
                                          int row0, int l16, int lg, f32x4 acc[16]) {
    #pragma unroll
    for (int i = 0; i < 16; ++i) acc[i] = (f32x4)0.0f;
    #pragma unroll
    for (int ks = 0; ks < 8; ++ks) {
        half8 a = *(const half8*)(A + (size_t)(row0 + l16) * ND + ks * 32 + lg * 8);
        #pragma unroll
        for (int ct = 0; ct < 16; ++ct) {
            half8 b = *(const half8*)(Bt + (size_t)(ct * 16 + l16) * ND + ks * 32 + lg * 8);
            acc[ct] = mfma_16x16x32(a, b, acc[ct]);
        }
    }
}

__global__ __launch_bounds__(256) void k_proj(const _Float16* __restrict__ h16,
                                              const _Float16* __restrict__ Wlt,
                                              const _Float16* __restrict__ Wgt,
                                              const _Float16* __restrict__ Wvt,
                                              _Float16* __restrict__ zn,
                                              _Float16* __restrict__ zg,
                                              _Float16* __restrict__ v16,
                                              float* __restrict__ sq) {
    const int mode = blockIdx.y;
    const _Float16* Bt = mode == 0 ? Wlt : mode == 1 ? Wgt : Wvt;
    _Float16* o16      = mode == 0 ? zn  : mode == 1 ? zg  : v16;
    const int w = threadIdx.x >> 6, l = threadIdx.x & 63;
    const int l16 = l & 15, lg = l >> 4;
    const int row0 = blockIdx.x * 64 + w * 16;
    f32x4 acc[16];
    gemm_core(h16, Bt, row0, l16, lg, acc);

    if (mode == 2) {
        #pragma unroll
        for (int ct = 0; ct < 16; ++ct)
            #pragma unroll
            for (int r = 0; r < 4; ++r)
                o16[(size_t)(row0 + lg * 4 + r) * ND + ct * 16 + l16] = (_Float16)acc[ct][r];
        return;
    }
    float n2[4] = {0.f, 0.f, 0.f, 0.f};
    #pragma unroll
    for (int ct = 0; ct < 16; ++ct)
        #pragma unroll
        for (int r = 0; r < 4; ++r) n2[r] += acc[ct][r] * acc[ct][r];
    #pragma unroll
    for (int m = 1; m < 16; m <<= 1) {
        #pragma unroll
        for (int r = 0; r < 4; ++r) n2[r] += __shfl_xor(n2[r], m);
    }
    if (mode == 0) {
        float ri[4];
        #pragma unroll
        for (int r = 0; r < 4; ++r) ri[r] = 1.0f / fmaxf(sqrtf(n2[r]), 1e-8f);
        #pragma unroll
        for (int ct = 0; ct < 16; ++ct)
            #pragma unroll
            for (int r = 0; r < 4; ++r)
                o16[(size_t)(row0 + lg * 4 + r) * ND + ct * 16 + l16] =
                    (_Float16)(acc[ct][r] * ri[r]);
    } else {
        #pragma unroll
        for (int ct = 0; ct < 16; ++ct)
            #pragma unroll
            for (int r = 0; r < 4; ++r)
                o16[(size_t)(row0 + lg * 4 + r) * ND + ct * 16 + l16] = (_Float16)acc[ct][r];
        if (l16 == 0) {
            #pragma unroll
            for (int r = 0; r < 4; ++r) sq[row0 + lg * 4 + r] = n2[r];
        }
    }
}

// v16 [b][n][d] -> vT [b][d][n]
__global__ __launch_bounds__(256) void k_tr(const _Float16* __restrict__ v16,
                                            _Float16* __restrict__ vT) {
    __shared__ _Float16 t[64][72];
    const int b = blockIdx.z, n0 = blockIdx.x * 64, d0 = blockIdx.y * 64;
    const int tj = threadIdx.x & 63, ti = threadIdx.x >> 6;
    #pragma unroll
    for (int i = 0; i < 16; ++i)
        t[ti + i * 4][tj] = v16[(size_t)(b * NN + n0 + ti + i * 4) * ND + d0 + tj];
    __syncthreads();
    #pragma unroll
    for (int i = 0; i < 16; ++i)
        vT[(size_t)(b * ND + d0 + ti + i * 4) * NN + n0 + tj] = t[tj][ti + i * 4];
}

// ---------------- score GEMM v5: 2 tk-tiles/block (shared tq), tri-buf, vmcnt(6) --
// grid 1088 = 4 bm x 272 pairs, XCD-swizzled so each XCD works one bm region.
// Per BK=32 step: stage(s+2), compute both tiles (12 ds_reads -> 32 MFMA/wave).
__global__ __launch_bounds__(256, 2) void k_score(const _Float16* __restrict__ zn,
                                                  const _Float16* __restrict__ zg,
                                                  const float* __restrict__ sqg,
                                                  _Float16* __restrict__ P,
                                                  float* __restrict__ degpart) {
    const int orig = blockIdx.x;
    const int wgid = (orig & 7) * (NB * 2 * NPAIR / 8) + (orig >> 3);  // bijective XCD swizzle
    const int bm = wgid / NPAIR;
    int s = wgid % NPAIR;
    const int b = bm >> 1, mat = bm & 1;
    int tq = 0;
    while (s >= (tq + 2) / 2) { s -= (tq + 2) / 2; ++tq; }
    const int tk0 = 2 * s;
    const bool has1 = (tk0 + 1) <= tq;
    const int tk1 = has1 ? tk0 + 1 : tk0;     // singleton: duplicate compute, skip epilogue

    const char* z = (const char*)((mat ? zg : zn) + (size_t)b * NN * ND);
    const float* sqb = sqg + (size_t)b * NN;
    const int w = threadIdx.x >> 6, lane = threadIdx.x & 63;
    const int l16 = lane & 15, lg = lane >> 4;
    const int wr = w >> 1, wc = w & 1;

    __shared__ char At[3][2][8192], Bq[3][8192];

    const char* zk0p = z + (size_t)tk0 * 128 * 512;
    const char* zk1p = z + (size_t)tk1 * 128 * 512;
    const char* zqp  = z + (size_t)tq  * 128 * 512;

    auto STAGE = [&](int bufi, int s_) {
        stage_side(zk0p + s_ * 64, 512, &At[bufi][0][0]);
        stage_side(zk1p + s_ * 64, 512, &At[bufi][1][0]);
        stage_side(zqp  + s_ * 64, 512, &Bq[bufi][0]);
    };

    f32x4 acc[2][4][4];
    #pragma unroll
    for (int t = 0; t < 2; ++t)
        #pragma unroll
        for (int i = 0; i < 4; ++i)
            #pragma unroll
            for (int j = 0; j < 4; ++j) acc[t][i][j] = (f32x4)0.f;

    STAGE(0, 0);
    STAGE(1, 1);
    BAR_V6();                                  // stage0 landed, stage1 in flight

    #pragma unroll
    for (int st = 0; st < 8; ++st) {
        if (st < 6) STAGE((st + 2) % 3, st + 2);
        const int cb = st % 3;
        half8 a0[4], a1[4], bq[4];
        #pragma unroll
        for (int i = 0; i < 4; ++i) {
            const int kr = wr * 64 + i * 16 + l16;
            a0[i] = ldsfrag(&At[cb][0][0], kr, lg);
            a1[i] = ldsfrag(&At[cb][1][0], kr, lg);
            bq[i] = ldsfrag(&Bq[cb][0], wc * 64 + i * 16 + l16, lg);
        }
        #pragma unroll
        for (int di = 0; di < 4; ++di)
            #pragma unroll
            for (int qi = 0; qi < 4; ++qi) {
                acc[0][di][qi] = mfma_16x16x32(a0[di], bq[qi], acc[0][di][qi]);
                acc[1][di][qi] = mfma_16x16x32(a1[di], bq[qi], acc[1][di][qi]);
            }
        if (st < 6) BAR_V6();
        else if (st == 6) BAR_V0();
    }

    // ---- epilogue per tile: transform, P write, degree partials
    float sqq[4];
    if (mat) {
        #pragma unroll
        for (int qi = 0; qi < 4; ++qi)
            sqq[qi] = sqb[tq * 128 + wc * 64 + qi * 16 + l16];
    }
    #pragma unroll
    for (int t01 = 0; t01 < 2; ++t01) {
        if (t01 == 1 && !has1) break;
        const int tk = t01 ? tk1 : tk0;
        const int tile = tri32(tq) + tk;
        _Float16* Pt = P + (size_t)(bm * TRI + tile) * 16384;
        float dsum[4] = {0.f, 0.f, 0.f, 0.f};
        #pragma unroll
        for (int di = 0; di < 4; ++di) {
            const int kl = wr * 64 + di * 16 + lg * 4;
            const int kg = tk * 128 + kl;
            f32x4 sqk;
            if (mat) sqk = *(const f32x4*)(sqb + kg);
            #pragma unroll
            for (int qi = 0; qi < 4; ++qi) {
                const int qg = tq * 128 + wc * 64 + qi * 16 + l16;
                half4 hv;
                #pragma unroll
                for (int r = 0; r < 4; ++r) {
                    const bool msk = (kg + r) < qg;        // causal + zero-diag
                    float p;
                    if (mat) p = msk ? __expf(-0.5f * (sqq[qi] + sqk[r] - 2.f * acc[t01][di][qi][r])) : 0.f;
                    else     p = msk ? fmaxf(acc[t01][di][qi][r], 0.f) : 0.f;
                    dsum[qi] += p;
                    hv[r] = (_Float16)p;
                }
                *(half4*)(Pt + (size_t)(wc * 64 + qi * 16 + l16) * 128 + kl) = hv;
            }
        }
        #pragma unroll
        for (int qi = 0; qi < 4; ++qi) {
            dsum[qi] += __shfl_xor(dsum[qi], 16);
            dsum[qi] += __shfl_xor(dsum[qi], 32);
        }
        if (lg == 0) {
            #pragma unroll
            for (int qi = 0; qi < 4; ++qi)
                degpart[(size_t)(bm * TRI + tile) * 256 + wr * 128 + wc * 64 + qi * 16 + l16] = dsum[qi];
        }
    }
}

// ---------------- PV GEMM: BK=32, tri-buffer, counted vmcnt, XCD swizzle ----------
__global__ __launch_bounds__(256, 3) void k_pv(const _Float16* __restrict__ P,
                                               const _Float16* __restrict__ vT,
                                               _Float16* __restrict__ part,
                                               int CHUNK, int NCH) {
    const int orig = blockIdx.x;
    const int nq = gridDim.x >> 3;
    const int wgid = (orig & 7) * nq + (orig >> 3);   // bijective XCD swizzle
    const int b = wgid / (4 * NCH);
    const int bx = wgid % (4 * NCH);
    const int dh = bx & 1, mat = (bx >> 1) & 1;
    int x = NCH - 1 - (bx >> 2);             // reversed: long chunks first per XCD
    int tq = 0, cum = 0;
    for (;;) {
        const int nc = (tq + CHUNK) / CHUNK;  // ceil((tq+1)/CHUNK)
        if (x < nc) break;
        x -= nc; cum += nc; ++tq;
    }
    const int c = x;
    const int kt0 = c * CHUNK;
    const int ktE = (kt0 + CHUNK < tq + 1) ? kt0 + CHUNK : tq + 1;
    const int NS = (ktE - kt0) * 4;          // BK=32 steps

    const int w = threadIdx.x >> 6, lane = threadIdx.x & 63;
    const int l16 = lane & 15, lg = lane >> 4;
    const int wr = w >> 1, wc = w & 1;

    __shared__ char At[3][8192], Bp[3][8192];

    const char* vTb = (const char*)(vT + (size_t)b * ND * NN) + (size_t)dh * 128 * (NN * 2);
    const char* Pbase = (const char*)(P + (size_t)((b * 2 + mat) * TRI + tri32(tq)) * 16384);

    auto STAGE = [&](int bufi, int j_) {
        const int kt = kt0 + (j_ >> 2), sub = j_ & 3;
        stage_side(vTb + (size_t)kt * 256 + sub * 64, (size_t)NN * 2, &At[bufi][0]);
        stage_side(Pbase + (size_t)kt * 32768 + sub * 64, 256, &Bp[bufi][0]);
    };

    f32x4 acc[4][4];
    #pragma unroll
    for (int i = 0; i < 4; ++i)
        #pragma unroll
        for (int j = 0; j < 4; ++j) acc[i][j] = (f32x4)0.f;

    STAGE(0, 0);
    STAGE(1, 1);
    BAR_V4();

    for (int s = 0; s < NS; ++s) {
        if (s + 2 < NS) STAGE((s + 2) % 3, s + 2);
        const int cb = s % 3;
        half8 a[4], bp[4];
        #pragma unroll
        for (int i = 0; i < 4; ++i) {
            a[i]  = ldsfrag(&At[cb][0], wr * 64 + i * 16 + l16, lg);
            bp[i] = ldsfrag(&Bp[cb][0], wc * 64 + i * 16 + l16, lg);
        }
        #pragma unroll
        for (int di = 0; di < 4; ++di)
            #pragma unroll
            for (int qi = 0; qi < 4; ++qi)
                acc[di][qi] = mfma_16x16x32(a[di], bp[qi], acc[di][qi]);
        if (s + 2 < NS) BAR_V4();
        else if (s + 1 < NS) BAR_V0();
    }

    _Float16* sl = part + (size_t)(((b * NCH + cum + c) * 2 + dh) * 2 + mat) * 16384;
    #pragma unroll
    for (int di = 0; di < 4; ++di) {
        const int dl = wr * 64 + di * 16 + lg * 4;
        #pragma unroll
        for (int qi = 0; qi < 4; ++qi) {
            half4 hv;
            #pragma unroll
            for (int r = 0; r < 4; ++r) hv[r] = (_Float16)acc[di][qi][r];
            *(half4*)(sl + (size_t)(wc * 64 + qi * 16 + l16) * 128 + dl) = hv;
        }
    }
}

// ---------------- fused combine + normalize + @Wo -> out ----------------
// grid (32, NB), 512 thr. Sums degree partials, combines PV chunk partials
// into a padded LDS tile, then GEMMs with Wot (global) and writes f32 out.
__global__ __launch_bounds__(512) void k_combo(const _Float16* __restrict__ part,
                                               const float* __restrict__ degpart,
                                               const _Float16* __restrict__ Wot,
                                               float* __restrict__ out,
                                               int CHUNK, int NCH) {
    const int tq = blockIdx.x, b = blockIdx.y;
    __shared__ _Float16 ot_t[128][264];      // +8 f16 pad -> 528B rows (2-way free)
    __shared__ float rl[128], rg[128];

    if (threadIdx.x < 256) {
        const int i = threadIdx.x & 127;
        const int m = threadIdx.x >> 7;
        const float* dp = degpart + (size_t)((b * 2 + m) * TRI + tri32(tq)) * 256 + i;
        float d = 0.f;
        for (int tk = 0; tk <= tq; ++tk)
            d += dp[(size_t)tk * 256] + dp[(size_t)tk * 256 + 128];
        (m ? rg : rl)[i] = (m ? 0.1f : 0.9f) / fmaxf(d, 1e-8f);
    }
    __syncthreads();

    int cum = 0;
    for (int t = 0; t < tq; ++t) cum += (t + CHUNK) / CHUNK;
    const int nc = (tq + CHUNK) / CHUNK;
    #pragma unroll
    for (int it = 0; it < 8; ++it) {
        const int f = it * 4096 + threadIdx.x * 8;   // 32768 f16 total
        const int dh = f >> 14, rem = f & 16383;
        const int row = rem >> 7, col = rem & 127;
        float s_l[8] = {0,0,0,0,0,0,0,0}, s_g[8] = {0,0,0,0,0,0,0,0};
        const _Float16* p0 = part + (size_t)(((b * NCH + cum) * 2 + dh) * 2) * 16384 + rem;
        for (int c = 0; c < nc; ++c) {
            half8 xl = *(const half8*)(p0 + (size_t)c * 4 * 16384);
            half8 xg = *(const half8*)(p0 + (size_t)c * 4 * 16384 + 16384);
            #pragma unroll
            for (int k = 0; k < 8; ++k) { s_l[k] += (float)xl[k]; s_g[k] += (float)xg[k]; }
        }
        half8 o;
        #pragma unroll
        for (int k = 0; k < 8; ++k)
            o[k] = (_Float16)(rl[row] * s_l[k] + rg[row] * s_g[k]);
        *(half8*)&ot_t[row][dh * 128 + col] = o;
    }
    __syncthreads();

    // GEMM: out[tq-tile rows][256] = ot_t (LDS) x Wot^T (global)
    const int w = threadIdx.x >> 6, l = threadIdx.x & 63;
    const int l16 = l & 15, lg = l >> 4;
    const int row0 = w * 16;
    f32x4 acc[16];
    #pragma unroll
    for (int i = 0; i < 16; ++i) acc[i] = (f32x4)0.f;
    #pragma unroll
    for (int ks = 0; ks < 8; ++ks) {
        half8 a = *(const half8*)&ot_t[row0 + l16][ks * 32 + lg * 8];
        #pragma unroll
        for (int ct = 0; ct < 16; ++ct) {
            half8 bw = *(const half8*)(Wot + (size_t)(ct * 16 + l16) * ND + ks * 32 + lg * 8);
            acc[ct] = mfma_16x16x32(a, bw, acc[ct]);
        }
    }
    #pragma unroll
    for (int ct = 0; ct < 16; ++ct)
        #pragma unroll
        for (int r = 0; r < 4; ++r)
            out[(size_t)(b * NN + tq * 128 + row0 + lg * 4 + r) * ND + ct * 16 + l16] = acc[ct][r];
}

extern "C" void kernel_launch(void* const* d_in, const int* in_sizes, int n_in,
                              void* d_out, int out_size, void* d_ws, size_t ws_size,
                              hipStream_t stream) {
    const float* h  = (const float*)d_in[0];
    const float* Wl = (const float*)d_in[2];
    const float* Wg = (const float*)d_in[3];
    const float* Wv = (const float*)d_in[4];
    const float* Wo = (const float*)d_in[5];
    float* out = (float*)d_out;

    uint8_t* base = (uint8_t*)d_ws;
    size_t off = 0;
    auto alloc = [&](size_t bytes) -> void* {
        void* r = base + off;
        off = (off + bytes + 255) & ~(size_t)255;
        return r;
    };
    const size_t bnd = (size_t)NB * NN * ND;
    _Float16* h16 = (_Float16*)alloc(bnd * 2);     // reused as vT after k_proj
    _Float16* Wlt = (_Float16*)alloc(ND * ND * 2);
    _Float16* Wgt = (_Float16*)alloc(ND * ND * 2);
    _Float16* Wvt = (_Float16*)alloc(ND * ND * 2);
    _Float16* Wot = (_Float16*)alloc(ND * ND * 2);
    _Float16* zn  = (_Float16*)alloc(bnd * 2);
    _Float16* zg  = (_Float16*)alloc(bnd * 2);
    _Float16* v16 = (_Float16*)alloc(bnd * 2);
    float*    sq  = (float*)alloc((size_t)NB * NN * 4);
    _Float16* P   = (_Float16*)alloc((size_t)NB * 2 * TRI * 16384 * 2);   // 69 MB
    float* degpart = (float*)alloc((size_t)NB * 2 * TRI * 256 * 4);       // 2.2 MB
    _Float16* vT = h16;                            // alias: h16 dead after k_proj

    // split-K chunking with ws fallback
    int CHUNK = 8, NCH = 0;
    for (;;) {
        NCH = 0;
        for (int t = 0; t < 32; ++t) NCH += (t + CHUNK) / CHUNK;
        if (off + (size_t)NB * NCH * 4 * 16384 * 2 + 256 <= ws_size || CHUNK >= 32) break;
        CHUNK *= 2;
    }
    _Float16* part = (_Float16*)alloc((size_t)NB * NCH * 4 * 16384 * 2);

    k_cvt_h<<<bnd / 4 / 256, 256, 0, stream>>>(h, h16);
    k_wt<<<dim3(ND, 4), 256, 0, stream>>>(Wl, Wg, Wv, Wo, Wlt, Wgt, Wvt, Wot);
    k_proj<<<dim3(NB * NN / 64, 3), 256, 0, stream>>>(h16, Wlt, Wgt, Wvt, zn, zg, v16, sq);
    k_tr<<<dim3(NN / 64, ND / 64, NB), 256, 0, stream>>>(v16, vT);
    k_score<<<NB * 2 * NPAIR, 256, 0, stream>>>(zn, zg, sq, P, degpart);
    k_pv<<<4 * NCH * NB, 256, 0, stream>>>(P, vT, part, CHUNK, NCH);
    k_combo<<<dim3(32, NB), 512, 0, stream>>>(part, degpart, Wot, out, CHUNK, NCH);
}